// Round 2
// baseline (101.561 us; speedup 1.0000x reference)
//
#include <hip/hip_runtime.h>
#include <math.h>

// Problem constants (from reference)
#define FH 64    // feature map H (axis indexed by x)
#define FW 64    // feature map W (axis indexed by y)
#define FC 256   // channels
#define PP 7     // pool output dim
#define NROI 256

// Exact replication of reference _bin_bounds integer math.
// lo = floor(lo_f*size); hi = ceil(hi_f*size); span = max(hi-lo,1)
// start_i = lo + floor(i*span/P); end_i = lo + ceil((i+1)*span/P)
// len = max(end-start,1); start clipped to [0,size-1]
__device__ __forceinline__ void bin_bounds(int lo, int span, int idx, int size,
                                           int& start, int& len) {
    int s0 = lo + (idx * span) / PP;                   // nonneg -> floor div
    int e0 = lo + ((idx + 1) * span + (PP - 1)) / PP;  // ceil div (nonneg)
    int l = e0 - s0;
    len = l > 1 ? l : 1;
    int s = s0 < 0 ? 0 : s0;
    start = s > (size - 1) ? (size - 1) : s;
}

// One 64-lane wave per (r, i) output row: computes all 7 j-bins.
// sx outermost so that all ~xlen*sum(ylen) loads of a feature row issue
// independently (deep MLP: ~20 outstanding loads/wave hides L2 latency
// even at low occupancy). lane = 4-channel group (float4), coalesced 1KB
// per load instruction.
__global__ __launch_bounds__(64) void roi_pool_row_kernel(
        const float* __restrict__ feat,   // (FH, FW, FC)
        const float* __restrict__ rois,   // (NROI, 4): x1,y1,x2,y2
        float* __restrict__ out)          // (NROI, PP, PP, FC)
{
    const int lane = threadIdx.x;         // 0..63
    const int row_id = blockIdx.x;        // r*PP + i
    const int i = row_id % PP;
    const int r = row_id / PP;

    const float x1 = rois[r * 4 + 0];
    const float y1 = rois[r * 4 + 1];
    const float x2 = rois[r * 4 + 2];
    const float y2 = rois[r * 4 + 3];

    const int xlo = (int)floorf(x1 * (float)FH);
    int xspan = (int)ceilf(x2 * (float)FH) - xlo;
    xspan = xspan > 1 ? xspan : 1;
    const int ylo = (int)floorf(y1 * (float)FW);
    int yspan = (int)ceilf(y2 * (float)FW) - ylo;
    yspan = yspan > 1 ? yspan : 1;

    int xs, xlen;
    bin_bounds(xlo, xspan, i, FH, xs, xlen);

    int ys[PP], ylen[PP];
#pragma unroll
    for (int j = 0; j < PP; ++j) {
        bin_bounds(ylo, yspan, j, FW, ys[j], ylen[j]);
    }

    const float4* f4 = (const float4*)feat;   // (FH, FW, FC/4)
    float4 acc[PP];
#pragma unroll
    for (int j = 0; j < PP; ++j)
        acc[j] = make_float4(-INFINITY, -INFINITY, -INFINITY, -INFINITY);

    for (int sx = 0; sx < xlen; ++sx) {
        int x = xs + sx;
        x = x > (FH - 1) ? (FH - 1) : x;
        const float4* frow = f4 + (size_t)(x * FW) * (FC / 4);
#pragma unroll
        for (int j = 0; j < PP; ++j) {
            for (int sy = 0; sy < ylen[j]; ++sy) {
                int y = ys[j] + sy;
                y = y > (FW - 1) ? (FW - 1) : y;
                float4 v = frow[y * (FC / 4) + lane];
                acc[j].x = fmaxf(acc[j].x, v.x);
                acc[j].y = fmaxf(acc[j].y, v.y);
                acc[j].z = fmaxf(acc[j].z, v.z);
                acc[j].w = fmaxf(acc[j].w, v.w);
            }
        }
    }

    // out row (r, i, 0..6, :): 7 contiguous float4 stores per lane
    float4* orow = (float4*)out + (size_t)row_id * PP * (FC / 4);
#pragma unroll
    for (int j = 0; j < PP; ++j) {
        orow[j * (FC / 4) + lane] = acc[j];
    }
}

extern "C" void kernel_launch(void* const* d_in, const int* in_sizes, int n_in,
                              void* d_out, int out_size, void* d_ws, size_t ws_size,
                              hipStream_t stream) {
    const float* feat = (const float*)d_in[0];   // (1,64,64,256)
    const float* rois = (const float*)d_in[1];   // (1,256,4)
    float* out = (float*)d_out;                  // (1,256,7,7,256)

    const int grid = NROI * PP;   // one 64-lane wave per (r, i) row
    roi_pool_row_kernel<<<grid, 64, 0, stream>>>(feat, rois, out);
}

// Round 3
// 67.647 us; speedup vs baseline: 1.5013x; 1.5013x over previous
//
#include <hip/hip_runtime.h>
#include <math.h>

// Problem constants (from reference)
#define FH 64    // feature map H (axis indexed by x)
#define FW 64    // feature map W (axis indexed by y)
#define FC 256   // channels
#define PP 7     // pool output dim
#define NROI 256
#define CH 8     // loads in flight per chunk

// Exact replication of reference _bin_bounds integer math.
__device__ __forceinline__ void bin_bounds(int lo, int span, int idx, int size,
                                           int& start, int& len) {
    int s0 = lo + (idx * span) / PP;                   // nonneg -> floor div
    int e0 = lo + ((idx + 1) * span + (PP - 1)) / PP;  // ceil div (nonneg)
    int l = e0 - s0;
    len = l > 1 ? l : 1;
    int s = s0 < 0 ? 0 : s0;
    start = s > (size - 1) ? (size - 1) : s;
}

// One 64-lane wave per output cell (r,i,j). The xlen*ylen window is walked
// linearly with wave-uniform (sx,sy) counters in unrolled chunks of CH:
// CH independent global_load_dwordx4 issue back-to-back (no waitcnt between
// them), then one waitcnt + CH fmax groups. Tail slots of the last chunk
// re-load the final valid pixel (duplicate under max = no-op), so no
// divergent masking is needed. lane = 4-channel group, 1KB coalesced/load.
__global__ __launch_bounds__(256) void roi_pool_kernel(
        const float* __restrict__ feat,   // (FH, FW, FC)
        const float* __restrict__ rois,   // (NROI, 4): x1,y1,x2,y2
        float* __restrict__ out)          // (NROI, PP, PP, FC)
{
    int gtid = blockIdx.x * blockDim.x + threadIdx.x;
    int lane = gtid & 63;          // 4 channels per lane (float4)
    int cell = gtid >> 6;          // (r, i, j) output cell, < NROI*PP*PP

    int j = cell % PP;
    int t = cell / PP;
    int i = t % PP;
    int r = t / PP;

    float x1 = rois[r * 4 + 0];
    float y1 = rois[r * 4 + 1];
    float x2 = rois[r * 4 + 2];
    float y2 = rois[r * 4 + 3];

    int xlo = (int)floorf(x1 * (float)FH);
    int xspan = (int)ceilf(x2 * (float)FH) - xlo;
    xspan = xspan > 1 ? xspan : 1;
    int ylo = (int)floorf(y1 * (float)FW);
    int yspan = (int)ceilf(y2 * (float)FW) - ylo;
    yspan = yspan > 1 ? yspan : 1;

    int xs, xlen, ys, ylen;
    bin_bounds(xlo, xspan, i, FH, xs, xlen);   // along H (axis 0)
    bin_bounds(ylo, yspan, j, FW, ys, ylen);   // along W (axis 1)

    const float4* __restrict__ f4 = (const float4*)feat;   // (FH, FW, FC/4)
    float4 acc = make_float4(-INFINITY, -INFINITY, -INFINITY, -INFINITY);

    const int n = xlen * ylen;     // wave-uniform window size (<= ~100)
    int sx = 0, sy = 0;            // wave-uniform walk counters

    for (int p = 0; p < n; p += CH) {
        float4 v[CH];
#pragma unroll
        for (int u = 0; u < CH; ++u) {
            int x = xs + sx; x = x > (FH - 1) ? (FH - 1) : x;
            int y = ys + sy; y = y > (FW - 1) ? (FW - 1) : y;
            v[u] = f4[(x * FW + y) * (FC / 4) + lane];
            // advance only while more valid pixels remain (uniform cond)
            if (p + u + 1 < n) {
                int nsy = sy + 1;
                if (nsy == ylen) { sy = 0; sx++; } else { sy = nsy; }
            }
        }
#pragma unroll
        for (int u = 0; u < CH; ++u) {
            acc.x = fmaxf(acc.x, v[u].x);
            acc.y = fmaxf(acc.y, v[u].y);
            acc.z = fmaxf(acc.z, v[u].z);
            acc.w = fmaxf(acc.w, v[u].w);
        }
    }

    ((float4*)out)[(size_t)cell * (FC / 4) + lane] = acc;
}

extern "C" void kernel_launch(void* const* d_in, const int* in_sizes, int n_in,
                              void* d_out, int out_size, void* d_ws, size_t ws_size,
                              hipStream_t stream) {
    const float* feat = (const float*)d_in[0];   // (1,64,64,256)
    const float* rois = (const float*)d_in[1];   // (1,256,4)
    float* out = (float*)d_out;                  // (1,256,7,7,256)

    const int total_threads = NROI * PP * PP * 64;  // one wave per cell
    const int block = 256;
    const int grid = (total_threads + block - 1) / block;  // 3136
    roi_pool_kernel<<<grid, block, 0, stream>>>(feat, rois, out);
}